// Round 12
// baseline (479.172 us; speedup 1.0000x reference)
//
#include <hip/hip_runtime.h>
#include <hip/hip_bf16.h>

#define NP   19
#define EPB  16
#define BLK  256
#define RSTRIDE 4864

// Compact XOR-swizzled LDS layout (round-6 core, frozen):
//   s_Wa rows: 256 shorts (512B, pow2) -> 3-bit key (e&7)<<3 on short index
//   s_tB rows: 160 shorts (320B, 10 o-chunks) -> 2-bit key (e&3)<<3
#define ESA  256           // Wa e-stride (shorts)
#define PBSA (16*ESA)      // Wa K-half stride
#define ESB  160           // tB e-stride (shorts)
#define PBSB (16*ESB)      // tB K-half stride
#define CGS  392           // s_cgy16 e-stride (shorts); 784B rows, 16B-aligned.
// LDS: Wa 16384 ; tB 10752 ; cgy16 12544 -> 39680 B -> 4 blocks/CU.
// Ledger of structural lessons:
//  R1: __launch_bounds__ min=5 crushes VGPRs -> 540MB scratch spill. Keep 4.
//  R6: fully-unrolled K-loop, runtime->compile-time path metadata: 357us.
//  R7: per-element device atomicAdd resolves at the cross-XCD coherent point:
//      36M atomics = +406MB RMW traffic, +257us. Never per-element atomics.
//  R8-R10: fused scatter (CSR + block-segmented reduce + pre-gather) exactly
//      re-spends what it saves (fused 505 vs two-phase 485). Reverted.
//  R9: LDS 26.6KB did NOT raise residency past 4 blocks/CU.
//  R11: bf16 msg halves the round-trip: WRITE 140->70MB, total 485->469. BEST.
//  R12: wave-per-node gather -- lane c reads msg[e*144+c] (three contiguous
//      128B segments/edge) vs old 2B-at-32B-stride per-lane pattern.
#define MINBPC 4

typedef __attribute__((ext_vector_type(8))) short bf16x8;
typedef __attribute__((ext_vector_type(4))) float f32x4;

// ---- per-path metadata (compile-time after full unroll) ----
__device__ const int   d_io[NP]  = {0,0,0, 1,1,1,1,1,1,1, 2,2,2,2, 2,2,2,2,2};
__device__ const int   d_ii[NP]  = {0,1,2, 0,1,1,1,2,2,2, 0,1,1,1, 2,2,2,2,2};
__device__ const int   d_lf[NP]  = {0,1,2, 1,0,1,2,1,2,3, 2,1,2,3, 0,1,2,3,4};
__device__ const int   d_cgb[NP] = {0,1,10, 35,44,53,80,125,170,245, 350,375,420,495, 600,625,700,825,1000};
// s_cgy16 per-path base (shorts). Non-overlapping packing, total 389 <= CGS=392:
//   dI=5: p2@0(8) p7@8(24) p8@32(24) p9@56(24) p14@80(40) p15@120(40)
//         p16@160(40) p17@200(40) p18@240(40)
//   dI=3: p1@280(4) p4@284(12) p5@296(12) p6@308(12) p11@320(20) p12@340(20) p13@360(20)
//   dI=1: p0@380(1) p3@381(3) p10@384(5)
__device__ const int   d_cgyb[NP] = {380,280,0, 381,284,296,308, 8,32,56, 384,320,340,360, 80,120,160,200,240};
__device__ const float d_nrm5[5] = {1.0f, 0.57735026918962576f, 0.44721359549995794f,
                                    0.37796447300922722f, 0.33333333333333333f};

__device__ __forceinline__ unsigned short to_bf16(float v) {
    __hip_bfloat16 h = __float2bfloat16(v);
    return *reinterpret_cast<unsigned short*>(&h);
}
__device__ __forceinline__ float bf2f(unsigned short u) {
    unsigned int x = ((unsigned int)u) << 16;
    union { unsigned int i; float f; } c; c.i = x;
    return c.f;
}

// ---- fused setup: R swizzle (first RTB blocks) + CSR count (rest) ----
__global__ void k_rtcount(const float* __restrict__ R, unsigned short* __restrict__ Rt,
                          const int* __restrict__ Ma, int* __restrict__ cur, int E) {
    const int RTB = (NP * 16 * 64 * 8) / BLK;      // 608 (exact)
    if ((int)blockIdx.x < RTB) {
        const int i = blockIdx.x * BLK + threadIdx.x;  // over NP*16*64*8
        const int j    = i & 7;
        const int lane = (i >> 3) & 63;
        const int t    = (i >> 9) & 15;
        const int p    = i >> 13;
        const int r    = (lane >> 4) * 8 + j;
        const int col  = p * 256 + 16 * t + (lane & 15);
        float v = (r < 10) ? R[r * RSTRIDE + col] : 0.f;
        Rt[i] = to_bf16(v);
    } else {
        const int e = (blockIdx.x - RTB) * BLK + threadIdx.x;
        if (e < E) atomicAdd(&cur[Ma[e]], 1);
    }
}

// ---------------- Phase A: edge-major; W-GEMM and msg-GEMM both on MFMA ----------------
__global__ __launch_bounds__(BLK, MINBPC)
void se3_msg(const float* __restrict__ F,
             const float* __restrict__ Ys, const float* __restrict__ Rad,
             const float* __restrict__ cg, const unsigned short* __restrict__ Rt,
             const int* __restrict__ Mb,
             unsigned short* __restrict__ msg, const int nE)
{
    __shared__ __align__(16) unsigned short s_Wa[2 * PBSA];        // Wstack A-frag (two K-halves)
    __shared__ __align__(16) unsigned short s_tB[2 * PBSB + 256];  // tmpstack B-frag + overrun pad
    __shared__ __align__(16) unsigned short s_cgy16[EPB * CGS];    // precomputed cgY (bf16 compact)

    const int tid  = threadIdx.x;
    const int l    = tid & 15;
    const int eloc = tid >> 4;
    const int lane = tid & 63;
    const int wv   = tid >> 6;
    const int q    = lane >> 4;
    const int n16  = lane & 15;
    const int e    = blockIdx.x * EPB + eloc;
    const bool act = (e < nE);
    const int  es  = act ? e : 0;

    // F slice -> registers (compile-time indexed)
    float fv[9];
    {
        const int b = Mb[es];
        const float* Fb = F + (size_t)b * 144;
        fv[0] = Fb[l];
        #pragma unroll
        for (int i = 0; i < 3; ++i) fv[1 + i] = Fb[16 + l*3 + i];
        #pragma unroll
        for (int i = 0; i < 5; ++i) fv[4 + i] = Fb[64 + l*5 + i];
    }
    // Ys row -> registers (dead after cgY prologue)
    float y[25];
    {
        const float* yr = Ys + (size_t)es * 25;
        #pragma unroll
        for (int k = 0; k < 25; ++k) y[k] = yr[k];
    }
    // radii fragment (B operand of MFMA-1): B[k=r][n=e], K zero-padded 10->32
    bf16x8 radfrag;
    {
        const int k0 = q * 8;
        const int ge = blockIdx.x * EPB + n16;
        const bool a = (ge < nE);
        const float* rp = Rad + (size_t)(a ? ge : 0) * 10;
        #pragma unroll
        for (int j = 0; j < 8; ++j) {
            const int k = k0 + j;
            radfrag[j] = (short)((a && k < 10) ? to_bf16(rp[k]) : (unsigned short)0);
        }
    }

    const int keyB = (eloc & 3) << 3;      // tB swizzle key for our row
    const int rowB = eloc * ESB;

    // tb one-time zero (maintained incrementally afterwards); 10 used chunks
    {
        #pragma unroll
        for (int n = 0; n < 10; ++n) {
            const int off = (rowB + (n << 4) + l) ^ keyB;
            s_tB[off] = 0; s_tB[PBSB + off] = 0;
        }
    }

    // ---- PROLOGUE: precompute ALL cgY (19 paths) into s_cgy16, bf16 compact ----
    {
        #pragma unroll
        for (int p = 0; p < NP; ++p) {
            const int io = d_io[p], ii = d_ii[p], lf = d_lf[p];
            const int cgb = d_cgb[p], cb = d_cgyb[p];
            const int dO = 2*io + 1, dI = 2*ii + 1, dF = 2*lf + 1;
            const int nOI = dO * dI;
            const float nrm = d_nrm5[lf];
            #pragma unroll
            for (int jj = 0; jj < 2; ++jj) {
                const int j = l + 16*jj;
                if (j < nOI) {            // pruned at compile time when nOI <= 16*jj
                    const int o = j / dI, i = j - o*dI;
                    const float* cgp = cg + cgb + j*dF;
                    float s = 0.f;
                    #pragma unroll
                    for (int f = 0; f < dF; ++f) s += cgp[f] * y[lf*lf + f];
                    const int off = (dI == 1) ? o : (dI == 3) ? (o*4 + i) : (o*8 + i);
                    s_cgy16[eloc*CGS + cb + off] = to_bf16(s * nrm);
                }
            }
        }
    }
    __asm__ volatile("" ::: "memory");   // cgY visible (intra-wave, DS in-order)

    // Rt prefetch double-buffer: rf[pb] holds path p's 4 fragments
    bf16x8 rf[2][4];
    {
        const unsigned short* r0 = Rt + (size_t)(4*wv)*512 + lane*8;
        #pragma unroll
        for (int tt = 0; tt < 4; ++tt) rf[0][tt] = *reinterpret_cast<const bf16x8*>(r0 + tt*512);
    }

    f32x4 D[4];
    #pragma unroll
    for (int ee = 0; ee < 4; ++ee) D[ee] = (f32x4){0.f,0.f,0.f,0.f};

    // ---- K-block loop: FULLY UNROLLED. 10 x (2 paths staged -> 1 MFMA-2 K-step).
    #pragma unroll
    for (int kb = 0; kb < 10; ++kb) {
        #pragma unroll
        for (int pb = 0; pb < 2; ++pb) {
            const int p = 2*kb + pb;
            // prefetch next path's Rt fragments into the other buffer
            if (p + 1 < NP) {
                const unsigned short* rn = Rt + (size_t)(p+1)*8192 + (size_t)(4*wv)*512 + lane*8;
                #pragma unroll
                for (int tt = 0; tt < 4; ++tt)
                    rf[pb ^ 1][tt] = *reinterpret_cast<const bf16x8*>(rn + tt*512);
            }
            if (p < NP) {
                // MFMA-1 (swapped): D = R_p^T(16c x 32k) @ rad^T(32k x 16e)
                #pragma unroll
                for (int tt = 0; tt < 4; ++tt) {
                    f32x4 d = __builtin_amdgcn_mfma_f32_16x16x32_bf16(
                                  rf[pb][tt], radfrag, (f32x4){0.f,0.f,0.f,0.f}, 0, 0, 0);
                    short4 pk;
                    pk.x = (short)to_bf16(d[0]); pk.y = (short)to_bf16(d[1]);
                    pk.z = (short)to_bf16(d[2]); pk.w = (short)to_bf16(d[3]);
                    const int w = 4*wv + tt;
                    *reinterpret_cast<short4*>(
                        &s_Wa[pb*PBSA + (((n16 << 8) + (w << 4) + (q << 2)) ^ ((n16 & 7) << 3))]) = pk;
                }

                // path metadata (compile-time constants after unroll)
                const int io = d_io[p], ii = d_ii[p], cb = d_cgyb[p];
                const int dO = 2*io + 1;
                const int ob  = (io == 0) ? 0 : (io == 1) ? 1 : 4;

                // tmp[v=l, o] -> B-frag bf16 [e][n=ob+o][v]; zero only vacated slots.
                const unsigned short* cgw = &s_cgy16[eloc*CGS + cb];
                unsigned short* tbh = &s_tB[pb*PBSB];
                if (p == 3 || p == 4)        { tbh[(rowB + l) ^ keyB] = 0; }
                else if (p == 10 || p == 11) { tbh[(rowB + 16 + l) ^ keyB] = 0;
                                               tbh[(rowB + 32 + l) ^ keyB] = 0;
                                               tbh[(rowB + 48 + l) ^ keyB] = 0; }
                if (ii == 0) {
                    #pragma unroll
                    for (int o = 0; o < dO; ++o) {
                        const float c0 = bf2f(cgw[o]);
                        tbh[(rowB + ((ob + o) << 4) + l) ^ keyB] = to_bf16(fv[0]*c0);
                    }
                } else if (ii == 1) {
                    #pragma unroll
                    for (int o = 0; o < dO; ++o) {
                        const short4 c = *reinterpret_cast<const short4*>(&cgw[o*4]);
                        tbh[(rowB + ((ob + o) << 4) + l) ^ keyB] =
                            to_bf16(fv[1]*bf2f((unsigned short)c.x)
                                  + fv[2]*bf2f((unsigned short)c.y)
                                  + fv[3]*bf2f((unsigned short)c.z));
                    }
                } else {
                    #pragma unroll
                    for (int o = 0; o < dO; ++o) {
                        const bf16x8 c = *reinterpret_cast<const bf16x8*>(&cgw[o*8]);
                        tbh[(rowB + ((ob + o) << 4) + l) ^ keyB] =
                            to_bf16(fv[4]*bf2f((unsigned short)c[0])
                                  + fv[5]*bf2f((unsigned short)c[1])
                                  + fv[6]*bf2f((unsigned short)c[2])
                                  + fv[7]*bf2f((unsigned short)c[3])
                                  + fv[8]*bf2f((unsigned short)c[4]));
                    }
                }
            } else {
                // p == 19 pad: zero our W slots (A==0 kills stale tb of this K-half)
                const short4 z = {0, 0, 0, 0};
                #pragma unroll
                for (int tt = 0; tt < 4; ++tt) {
                    const int w = 4*wv + tt;
                    *reinterpret_cast<short4*>(
                        &s_Wa[pb*PBSA + (((n16 << 8) + (w << 4) + (q << 2)) ^ ((n16 & 7) << 3))]) = z;
                }
            }
        }
        __syncthreads();   // W (cross-wave w-tiles) staged for this K-block

        // MFMA-2 K-step: msg_e(16w x 16n) += Wstack_e(16x32) @ tmpstack_e(32x16)
        {
            const int kh = q >> 1;
            const int vh = (q & 1) << 3;
            #pragma unroll
            for (int ee = 0; ee < 4; ++ee) {
                const int eK   = 4*wv + ee;
                const bf16x8 Af = *reinterpret_cast<const bf16x8*>(
                    &s_Wa[kh*PBSA + (((eK << 8) + (n16 << 4) + vh) ^ ((eK & 7) << 3))]);
                const bf16x8 Bf = *reinterpret_cast<const bf16x8*>(
                    &s_tB[kh*PBSB + ((eK*ESB + (n16 << 4) + vh) ^ ((eK & 3) << 3))]);
                D[ee] = __builtin_amdgcn_mfma_f32_16x16x32_bf16(Af, Bf, D[ee], 0, 0, 0);
            }
        }
        __syncthreads();   // WAR: next K-block rewrites s_Wa / s_tB
    }

    // epilogue: D[row=w=q*4+r, col=oflat=n16] -> msg[e][oflat*16 + w] as bf16,
    // short4 (8B) stores; halves the msg round-trip vs fp32.
    if (n16 < 9) {
        #pragma unroll
        for (int ee = 0; ee < 4; ++ee) {
            const int eg = blockIdx.x * EPB + 4*wv + ee;
            if (eg < nE) {
                unsigned short* mp = msg + (size_t)eg * 144 + n16*16 + q*4;
                short4 pk;
                pk.x = (short)to_bf16(D[ee][0]); pk.y = (short)to_bf16(D[ee][1]);
                pk.z = (short)to_bf16(D[ee][2]); pk.w = (short)to_bf16(D[ee][3]);
                *reinterpret_cast<short4*>(mp) = pk;
            }
        }
    }
}

// ---------------- Phase B: wave-per-node gather (coalesced msg reads) ----------------
// Lane c of the node's wave accumulates msg columns {c, 64+c, 128+c(c<16)}:
// per edge the wave issues 3 contiguous 128B segments (was 2B loads at 32B
// stride per lane = 9 narrow transactions per row).
__global__ __launch_bounds__(BLK)
void se3_gather(const unsigned short* __restrict__ msg, const int* __restrict__ off,
                const int* __restrict__ eidx, const float* __restrict__ Nn,
                float* __restrict__ Out, const int nN)
{
    const int c  = threadIdx.x & 63;
    const int wv = threadIdx.x >> 6;
    const int n  = blockIdx.x * 4 + wv;
    if (n >= nN) return;

    const int i0 = off[n], i1 = off[n + 1];
    float s0 = 0.f, s1 = 0.f, s2 = 0.f;

    #pragma unroll 2
    for (int idx = i0; idx < i1; ++idx) {
        const int eid = eidx[idx];                      // wave-uniform (scalar load)
        const unsigned short* m = msg + (size_t)eid * 144;
        s0 += bf2f(m[c]);
        s1 += bf2f(m[64 + c]);
        if (c < 16) s2 += bf2f(m[128 + c]);
    }

    const float nn = Nn[n];
    float* orow = Out + (size_t)n * 144;
    // proven col->Out mapping (round 7): of==0 -> w ; 1..3 -> 16+w*3+(of-1) ;
    // 4..8 -> 64+w*5+(of-4), where of=col>>4, w=col&15.
    {
        const int of = c >> 4, w = c & 15;
        const int oidx = (of == 0) ? w : (16 + w*3 + (of - 1));
        orow[oidx] = s0 * nn;
    }
    {
        const int col = 64 + c;
        const int of = col >> 4, w = col & 15;          // of in 4..7
        orow[64 + w*5 + (of - 4)] = s1 * nn;
    }
    if (c < 16) {
        orow[64 + c*5 + 4] = s2 * nn;                   // col=128+c, of=8, w=c
    }
}

// ---------------- CSR build (by destination) ----------------
__global__ void k_scan(int* __restrict__ cur, int* __restrict__ off, int N) {
    __shared__ int part[BLK];
    const int t = threadIdx.x;
    const int K = (N + BLK - 1) / BLK;
    const int i0 = t * K, i1 = min(i0 + K, N);
    int s = 0;
    for (int i = i0; i < i1; ++i) s += cur[i];
    part[t] = s;
    __syncthreads();
    if (t == 0) {
        int a = 0;
        for (int j = 0; j < BLK; ++j) { int v = part[j]; part[j] = a; a += v; }
        off[N] = a;
    }
    __syncthreads();
    int a = part[t];
    for (int i = i0; i < i1; ++i) {
        int v = cur[i];
        off[i] = a;
        cur[i] = a;       // reuse as scatter cursor
        a += v;
    }
}

__global__ void k_scatter(const int* __restrict__ Ma, int* __restrict__ cur,
                          int* __restrict__ eidx, int E) {
    int e = blockIdx.x * blockDim.x + threadIdx.x;
    if (e < E) {
        int pos = atomicAdd(&cur[Ma[e]], 1);
        eidx[pos] = e;
    }
}

extern "C" void kernel_launch(void* const* d_in, const int* in_sizes, int n_in,
                              void* d_out, int out_size, void* d_ws, size_t ws_size,
                              hipStream_t stream) {
    const float* F   = (const float*)d_in[0];
    const float* R   = (const float*)d_in[1];
    const float* Ys  = (const float*)d_in[2];
    const float* Rad = (const float*)d_in[3];
    const float* cg  = (const float*)d_in[4];
    const float* Nn  = (const float*)d_in[5];
    const int*   Ma  = (const int*)d_in[6];
    const int*   Mb  = (const int*)d_in[7];
    float* Out = (float*)d_out;

    const int nE = in_sizes[6];   // edges
    const int nN = in_sizes[5];   // nodes

    // ws layout (float units): [cur nN][off nN+1][eidx nE][pad]
    //   [msg nE*144 bf16 = nE*72 f32][pad][Rt NP*16*64*8 bf16]
    int* wsI  = (int*)d_ws;
    int* cur  = wsI;
    int* off  = wsI + nN;
    int* eidx = wsI + 2*nN + 1;
    size_t msgOff = ((size_t)(2*nN + 1 + nE) + 63) & ~(size_t)63;
    unsigned short* msg16 = (unsigned short*)((float*)d_ws + msgOff);
    size_t rtOff = ((msgOff + (size_t)nE * 72) + 63) & ~(size_t)63;
    unsigned short* Rt = (unsigned short*)((float*)d_ws + rtOff);

    const int RTB = (NP * 16 * 64 * 8) / BLK;          // 608
    const int CNT = (nE + BLK - 1) / BLK;

    hipMemsetAsync(cur, 0, (size_t)nN * sizeof(int), stream);
    k_rtcount<<<RTB + CNT, BLK, 0, stream>>>(R, Rt, Ma, cur, nE);
    k_scan   <<<1, BLK, 0, stream>>>(cur, off, nN);
    k_scatter<<<CNT, BLK, 0, stream>>>(Ma, cur, eidx, nE);

    se3_msg   <<<(nE + EPB - 1) / EPB, BLK, 0, stream>>>(F, Ys, Rad, cg, Rt, Mb, msg16, nE);
    se3_gather<<<(nN + 3) / 4, BLK, 0, stream>>>(msg16, off, eidx, Nn, Out, nN);
}

// Round 14
// 472.597 us; speedup vs baseline: 1.0139x; 1.0139x over previous
//
#include <hip/hip_runtime.h>
#include <hip/hip_bf16.h>

#define NP   19
#define EPB  16
#define BLK  256
#define RSTRIDE 4864

// Compact XOR-swizzled LDS layout (round-6 core, frozen):
//   s_Wa rows: 256 shorts (512B, pow2) -> 3-bit key (e&7)<<3 on short index
//   s_tB rows: 160 shorts (320B, 10 o-chunks) -> 2-bit key (e&3)<<3
#define ESA  256           // Wa e-stride (shorts)
#define PBSA (16*ESA)      // Wa K-half stride
#define ESB  160           // tB e-stride (shorts)
#define PBSB (16*ESB)      // tB K-half stride
#define CGS  392           // s_cgy16 e-stride (shorts); 784B rows, 16B-aligned.
// LDS: Wa 16384 ; tB 10752 ; cgy16 12544 -> 39680 B -> 4 blocks/CU.
// Ledger of structural lessons:
//  R1: __launch_bounds__ min=5 crushes VGPRs -> 540MB scratch spill. Keep 4.
//  R6: fully-unrolled K-loop, runtime->compile-time path metadata: 357us.
//  R7: per-element device atomicAdd resolves at the cross-XCD coherent point:
//      36M atomics = +406MB RMW traffic, +257us. Never per-element atomics.
//  R8-R10: fused scatter exactly re-spends what it saves. Reverted.
//  R9: LDS 26.6KB did NOT raise residency past 4 blocks/CU.
//  R11: bf16 msg halves the round-trip: total 485->469. BEST.
//  R12: wave-per-node gather neutral (-10): transaction width wasn't the cost.
//  R13: msg written at CSR position pos[e] -> gather reads are fully
//      SEQUENTIAL (node's rows contiguous); no eidx lookup in gather.
//      (R13 bench was an infra failure, not a kernel result; resubmitted.)
#define MINBPC 4

typedef __attribute__((ext_vector_type(8))) short bf16x8;
typedef __attribute__((ext_vector_type(4))) float f32x4;

// ---- per-path metadata (compile-time after full unroll) ----
__device__ const int   d_io[NP]  = {0,0,0, 1,1,1,1,1,1,1, 2,2,2,2, 2,2,2,2,2};
__device__ const int   d_ii[NP]  = {0,1,2, 0,1,1,1,2,2,2, 0,1,1,1, 2,2,2,2,2};
__device__ const int   d_lf[NP]  = {0,1,2, 1,0,1,2,1,2,3, 2,1,2,3, 0,1,2,3,4};
__device__ const int   d_cgb[NP] = {0,1,10, 35,44,53,80,125,170,245, 350,375,420,495, 600,625,700,825,1000};
// s_cgy16 per-path base (shorts). Non-overlapping packing, total 389 <= CGS=392:
//   dI=5: p2@0(8) p7@8(24) p8@32(24) p9@56(24) p14@80(40) p15@120(40)
//         p16@160(40) p17@200(40) p18@240(40)
//   dI=3: p1@280(4) p4@284(12) p5@296(12) p6@308(12) p11@320(20) p12@340(20) p13@360(20)
//   dI=1: p0@380(1) p3@381(3) p10@384(5)
__device__ const int   d_cgyb[NP] = {380,280,0, 381,284,296,308, 8,32,56, 384,320,340,360, 80,120,160,200,240};
__device__ const float d_nrm5[5] = {1.0f, 0.57735026918962576f, 0.44721359549995794f,
                                    0.37796447300922722f, 0.33333333333333333f};

__device__ __forceinline__ unsigned short to_bf16(float v) {
    __hip_bfloat16 h = __float2bfloat16(v);
    return *reinterpret_cast<unsigned short*>(&h);
}
__device__ __forceinline__ float bf2f(unsigned short u) {
    unsigned int x = ((unsigned int)u) << 16;
    union { unsigned int i; float f; } c; c.i = x;
    return c.f;
}

// ---- fused setup: R swizzle (first RTB blocks) + CSR count (rest) ----
__global__ void k_rtcount(const float* __restrict__ R, unsigned short* __restrict__ Rt,
                          const int* __restrict__ Ma, int* __restrict__ cur, int E) {
    const int RTB = (NP * 16 * 64 * 8) / BLK;      // 608 (exact)
    if ((int)blockIdx.x < RTB) {
        const int i = blockIdx.x * BLK + threadIdx.x;  // over NP*16*64*8
        const int j    = i & 7;
        const int lane = (i >> 3) & 63;
        const int t    = (i >> 9) & 15;
        const int p    = i >> 13;
        const int r    = (lane >> 4) * 8 + j;
        const int col  = p * 256 + 16 * t + (lane & 15);
        float v = (r < 10) ? R[r * RSTRIDE + col] : 0.f;
        Rt[i] = to_bf16(v);
    } else {
        const int e = (blockIdx.x - RTB) * BLK + threadIdx.x;
        if (e < E) atomicAdd(&cur[Ma[e]], 1);
    }
}

// ---------------- Phase A: edge-major; W-GEMM and msg-GEMM both on MFMA ----------------
__global__ __launch_bounds__(BLK, MINBPC)
void se3_msg(const float* __restrict__ F,
             const float* __restrict__ Ys, const float* __restrict__ Rad,
             const float* __restrict__ cg, const unsigned short* __restrict__ Rt,
             const int* __restrict__ Mb, const int* __restrict__ pos,
             unsigned short* __restrict__ msg, const int nE)
{
    __shared__ __align__(16) unsigned short s_Wa[2 * PBSA];        // Wstack A-frag (two K-halves)
    __shared__ __align__(16) unsigned short s_tB[2 * PBSB + 256];  // tmpstack B-frag + overrun pad
    __shared__ __align__(16) unsigned short s_cgy16[EPB * CGS];    // precomputed cgY (bf16 compact)

    const int tid  = threadIdx.x;
    const int l    = tid & 15;
    const int eloc = tid >> 4;
    const int lane = tid & 63;
    const int wv   = tid >> 6;
    const int q    = lane >> 4;
    const int n16  = lane & 15;
    const int e    = blockIdx.x * EPB + eloc;
    const bool act = (e < nE);
    const int  es  = act ? e : 0;

    // F slice -> registers (compile-time indexed)
    float fv[9];
    {
        const int b = Mb[es];
        const float* Fb = F + (size_t)b * 144;
        fv[0] = Fb[l];
        #pragma unroll
        for (int i = 0; i < 3; ++i) fv[1 + i] = Fb[16 + l*3 + i];
        #pragma unroll
        for (int i = 0; i < 5; ++i) fv[4 + i] = Fb[64 + l*5 + i];
    }
    // Ys row -> registers (dead after cgY prologue)
    float y[25];
    {
        const float* yr = Ys + (size_t)es * 25;
        #pragma unroll
        for (int k = 0; k < 25; ++k) y[k] = yr[k];
    }
    // radii fragment (B operand of MFMA-1): B[k=r][n=e], K zero-padded 10->32
    bf16x8 radfrag;
    {
        const int k0 = q * 8;
        const int ge = blockIdx.x * EPB + n16;
        const bool a = (ge < nE);
        const float* rp = Rad + (size_t)(a ? ge : 0) * 10;
        #pragma unroll
        for (int j = 0; j < 8; ++j) {
            const int k = k0 + j;
            radfrag[j] = (short)((a && k < 10) ? to_bf16(rp[k]) : (unsigned short)0);
        }
    }
    // CSR write positions for this wave's 4 edges (wave-uniform -> scalar loads)
    int wpos[4];
    {
        #pragma unroll
        for (int ee = 0; ee < 4; ++ee) {
            const int eg = blockIdx.x * EPB + 4*wv + ee;
            wpos[ee] = (eg < nE) ? pos[eg] : 0;
        }
    }

    const int keyB = (eloc & 3) << 3;      // tB swizzle key for our row
    const int rowB = eloc * ESB;

    // tb one-time zero (maintained incrementally afterwards); 10 used chunks
    {
        #pragma unroll
        for (int n = 0; n < 10; ++n) {
            const int off = (rowB + (n << 4) + l) ^ keyB;
            s_tB[off] = 0; s_tB[PBSB + off] = 0;
        }
    }

    // ---- PROLOGUE: precompute ALL cgY (19 paths) into s_cgy16, bf16 compact ----
    {
        #pragma unroll
        for (int p = 0; p < NP; ++p) {
            const int io = d_io[p], ii = d_ii[p], lf = d_lf[p];
            const int cgb = d_cgb[p], cb = d_cgyb[p];
            const int dO = 2*io + 1, dI = 2*ii + 1, dF = 2*lf + 1;
            const int nOI = dO * dI;
            const float nrm = d_nrm5[lf];
            #pragma unroll
            for (int jj = 0; jj < 2; ++jj) {
                const int j = l + 16*jj;
                if (j < nOI) {            // pruned at compile time when nOI <= 16*jj
                    const int o = j / dI, i = j - o*dI;
                    const float* cgp = cg + cgb + j*dF;
                    float s = 0.f;
                    #pragma unroll
                    for (int f = 0; f < dF; ++f) s += cgp[f] * y[lf*lf + f];
                    const int off = (dI == 1) ? o : (dI == 3) ? (o*4 + i) : (o*8 + i);
                    s_cgy16[eloc*CGS + cb + off] = to_bf16(s * nrm);
                }
            }
        }
    }
    __asm__ volatile("" ::: "memory");   // cgY visible (intra-wave, DS in-order)

    // Rt prefetch double-buffer: rf[pb] holds path p's 4 fragments
    bf16x8 rf[2][4];
    {
        const unsigned short* r0 = Rt + (size_t)(4*wv)*512 + lane*8;
        #pragma unroll
        for (int tt = 0; tt < 4; ++tt) rf[0][tt] = *reinterpret_cast<const bf16x8*>(r0 + tt*512);
    }

    f32x4 D[4];
    #pragma unroll
    for (int ee = 0; ee < 4; ++ee) D[ee] = (f32x4){0.f,0.f,0.f,0.f};

    // ---- K-block loop: FULLY UNROLLED. 10 x (2 paths staged -> 1 MFMA-2 K-step).
    #pragma unroll
    for (int kb = 0; kb < 10; ++kb) {
        #pragma unroll
        for (int pb = 0; pb < 2; ++pb) {
            const int p = 2*kb + pb;
            // prefetch next path's Rt fragments into the other buffer
            if (p + 1 < NP) {
                const unsigned short* rn = Rt + (size_t)(p+1)*8192 + (size_t)(4*wv)*512 + lane*8;
                #pragma unroll
                for (int tt = 0; tt < 4; ++tt)
                    rf[pb ^ 1][tt] = *reinterpret_cast<const bf16x8*>(rn + tt*512);
            }
            if (p < NP) {
                // MFMA-1 (swapped): D = R_p^T(16c x 32k) @ rad^T(32k x 16e)
                #pragma unroll
                for (int tt = 0; tt < 4; ++tt) {
                    f32x4 d = __builtin_amdgcn_mfma_f32_16x16x32_bf16(
                                  rf[pb][tt], radfrag, (f32x4){0.f,0.f,0.f,0.f}, 0, 0, 0);
                    short4 pk;
                    pk.x = (short)to_bf16(d[0]); pk.y = (short)to_bf16(d[1]);
                    pk.z = (short)to_bf16(d[2]); pk.w = (short)to_bf16(d[3]);
                    const int w = 4*wv + tt;
                    *reinterpret_cast<short4*>(
                        &s_Wa[pb*PBSA + (((n16 << 8) + (w << 4) + (q << 2)) ^ ((n16 & 7) << 3))]) = pk;
                }

                // path metadata (compile-time constants after unroll)
                const int io = d_io[p], ii = d_ii[p], cb = d_cgyb[p];
                const int dO = 2*io + 1;
                const int ob  = (io == 0) ? 0 : (io == 1) ? 1 : 4;

                // tmp[v=l, o] -> B-frag bf16 [e][n=ob+o][v]; zero only vacated slots.
                const unsigned short* cgw = &s_cgy16[eloc*CGS + cb];
                unsigned short* tbh = &s_tB[pb*PBSB];
                if (p == 3 || p == 4)        { tbh[(rowB + l) ^ keyB] = 0; }
                else if (p == 10 || p == 11) { tbh[(rowB + 16 + l) ^ keyB] = 0;
                                               tbh[(rowB + 32 + l) ^ keyB] = 0;
                                               tbh[(rowB + 48 + l) ^ keyB] = 0; }
                if (ii == 0) {
                    #pragma unroll
                    for (int o = 0; o < dO; ++o) {
                        const float c0 = bf2f(cgw[o]);
                        tbh[(rowB + ((ob + o) << 4) + l) ^ keyB] = to_bf16(fv[0]*c0);
                    }
                } else if (ii == 1) {
                    #pragma unroll
                    for (int o = 0; o < dO; ++o) {
                        const short4 c = *reinterpret_cast<const short4*>(&cgw[o*4]);
                        tbh[(rowB + ((ob + o) << 4) + l) ^ keyB] =
                            to_bf16(fv[1]*bf2f((unsigned short)c.x)
                                  + fv[2]*bf2f((unsigned short)c.y)
                                  + fv[3]*bf2f((unsigned short)c.z));
                    }
                } else {
                    #pragma unroll
                    for (int o = 0; o < dO; ++o) {
                        const bf16x8 c = *reinterpret_cast<const bf16x8*>(&cgw[o*8]);
                        tbh[(rowB + ((ob + o) << 4) + l) ^ keyB] =
                            to_bf16(fv[4]*bf2f((unsigned short)c[0])
                                  + fv[5]*bf2f((unsigned short)c[1])
                                  + fv[6]*bf2f((unsigned short)c[2])
                                  + fv[7]*bf2f((unsigned short)c[3])
                                  + fv[8]*bf2f((unsigned short)c[4]));
                    }
                }
            } else {
                // p == 19 pad: zero our W slots (A==0 kills stale tb of this K-half)
                const short4 z = {0, 0, 0, 0};
                #pragma unroll
                for (int tt = 0; tt < 4; ++tt) {
                    const int w = 4*wv + tt;
                    *reinterpret_cast<short4*>(
                        &s_Wa[pb*PBSA + (((n16 << 8) + (w << 4) + (q << 2)) ^ ((n16 & 7) << 3))]) = z;
                }
            }
        }
        __syncthreads();   // W (cross-wave w-tiles) staged for this K-block

        // MFMA-2 K-step: msg_e(16w x 16n) += Wstack_e(16x32) @ tmpstack_e(32x16)
        {
            const int kh = q >> 1;
            const int vh = (q & 1) << 3;
            #pragma unroll
            for (int ee = 0; ee < 4; ++ee) {
                const int eK   = 4*wv + ee;
                const bf16x8 Af = *reinterpret_cast<const bf16x8*>(
                    &s_Wa[kh*PBSA + (((eK << 8) + (n16 << 4) + vh) ^ ((eK & 7) << 3))]);
                const bf16x8 Bf = *reinterpret_cast<const bf16x8*>(
                    &s_tB[kh*PBSB + ((eK*ESB + (n16 << 4) + vh) ^ ((eK & 3) << 3))]);
                D[ee] = __builtin_amdgcn_mfma_f32_16x16x32_bf16(Af, Bf, D[ee], 0, 0, 0);
            }
        }
        __syncthreads();   // WAR: next K-block rewrites s_Wa / s_tB
    }

    // epilogue: D[row=w=q*4+r, col=oflat=n16] -> msg[pos[e]][oflat*16 + w] as
    // bf16 short4 stores. Writing at the CSR position makes each node's rows
    // CONTIGUOUS for the gather (sequential stream, no eidx indirection).
    if (n16 < 9) {
        #pragma unroll
        for (int ee = 0; ee < 4; ++ee) {
            const int eg = blockIdx.x * EPB + 4*wv + ee;
            if (eg < nE) {
                unsigned short* mp = msg + (size_t)wpos[ee] * 144 + n16*16 + q*4;
                short4 pk;
                pk.x = (short)to_bf16(D[ee][0]); pk.y = (short)to_bf16(D[ee][1]);
                pk.z = (short)to_bf16(D[ee][2]); pk.w = (short)to_bf16(D[ee][3]);
                *reinterpret_cast<short4*>(mp) = pk;
            }
        }
    }
}

// ---------------- Phase B: node gather-reduce over CONTIGUOUS msg rows ----------------
__global__ __launch_bounds__(BLK)
void se3_gather(const unsigned short* __restrict__ msg, const int* __restrict__ off,
                const float* __restrict__ Nn,
                float* __restrict__ Out, const int nN)
{
    const int l = threadIdx.x & 15;
    const int g = threadIdx.x >> 4;
    const int n = blockIdx.x * 16 + g;
    if (n >= nN) return;

    const int i0 = off[n], i1 = off[n + 1];
    float s[9];
    #pragma unroll
    for (int j = 0; j < 9; ++j) s[j] = 0.f;

    for (int idx = i0; idx < i1; ++idx) {
        const unsigned short* m = msg + (size_t)idx * 144 + l;   // contiguous rows
        #pragma unroll
        for (int j = 0; j < 9; ++j) s[j] += bf2f(m[j * 16]);
    }

    const float nn = Nn[n];
    float* orow = Out + (size_t)n * 144;
    orow[l] = s[0] * nn;
    #pragma unroll
    for (int o = 0; o < 3; ++o) orow[16 + l*3 + o] = s[1+o] * nn;
    #pragma unroll
    for (int o = 0; o < 5; ++o) orow[64 + l*5 + o] = s[4+o] * nn;
}

// ---------------- CSR build (by destination) ----------------
__global__ void k_scan(int* __restrict__ cur, int* __restrict__ off, int N) {
    __shared__ int part[BLK];
    const int t = threadIdx.x;
    const int K = (N + BLK - 1) / BLK;
    const int i0 = t * K, i1 = min(i0 + K, N);
    int s = 0;
    for (int i = i0; i < i1; ++i) s += cur[i];
    part[t] = s;
    __syncthreads();
    if (t == 0) {
        int a = 0;
        for (int j = 0; j < BLK; ++j) { int v = part[j]; part[j] = a; a += v; }
        off[N] = a;
    }
    __syncthreads();
    int a = part[t];
    for (int i = i0; i < i1; ++i) {
        int v = cur[i];
        off[i] = a;
        cur[i] = a;       // reuse as scatter cursor
        a += v;
    }
}

// pos[e] = CSR slot of edge e (inverse permutation; msg written there directly)
__global__ void k_scatter(const int* __restrict__ Ma, int* __restrict__ cur,
                          int* __restrict__ pos, int E) {
    int e = blockIdx.x * blockDim.x + threadIdx.x;
    if (e < E) {
        pos[e] = atomicAdd(&cur[Ma[e]], 1);
    }
}

extern "C" void kernel_launch(void* const* d_in, const int* in_sizes, int n_in,
                              void* d_out, int out_size, void* d_ws, size_t ws_size,
                              hipStream_t stream) {
    const float* F   = (const float*)d_in[0];
    const float* R   = (const float*)d_in[1];
    const float* Ys  = (const float*)d_in[2];
    const float* Rad = (const float*)d_in[3];
    const float* cg  = (const float*)d_in[4];
    const float* Nn  = (const float*)d_in[5];
    const int*   Ma  = (const int*)d_in[6];
    const int*   Mb  = (const int*)d_in[7];
    float* Out = (float*)d_out;

    const int nE = in_sizes[6];   // edges
    const int nN = in_sizes[5];   // nodes

    // ws layout (float units): [cur nN][off nN+1][pos nE][pad]
    //   [msg nE*144 bf16 = nE*72 f32][pad][Rt NP*16*64*8 bf16]
    int* wsI  = (int*)d_ws;
    int* cur  = wsI;
    int* off  = wsI + nN;
    int* pos  = wsI + 2*nN + 1;
    size_t msgOff = ((size_t)(2*nN + 1 + nE) + 63) & ~(size_t)63;
    unsigned short* msg16 = (unsigned short*)((float*)d_ws + msgOff);
    size_t rtOff = ((msgOff + (size_t)nE * 72) + 63) & ~(size_t)63;
    unsigned short* Rt = (unsigned short*)((float*)d_ws + rtOff);

    const int RTB = (NP * 16 * 64 * 8) / BLK;          // 608
    const int CNT = (nE + BLK - 1) / BLK;

    hipMemsetAsync(cur, 0, (size_t)nN * sizeof(int), stream);
    k_rtcount<<<RTB + CNT, BLK, 0, stream>>>(R, Rt, Ma, cur, nE);
    k_scan   <<<1, BLK, 0, stream>>>(cur, off, nN);
    k_scatter<<<CNT, BLK, 0, stream>>>(Ma, cur, pos, nE);

    se3_msg   <<<(nE + EPB - 1) / EPB, BLK, 0, stream>>>(F, Ys, Rad, cg, Rt, Mb, pos, msg16, nE);
    se3_gather<<<(nN + 15) / 16, BLK, 0, stream>>>(msg16, off, Nn, Out, nN);
}

// Round 15
// 462.097 us; speedup vs baseline: 1.0370x; 1.0227x over previous
//
#include <hip/hip_runtime.h>
#include <hip/hip_bf16.h>

#define NP   19
#define EPB  16
#define BLK  256
#define RSTRIDE 4864

// Compact XOR-swizzled LDS layout (round-6 core, frozen):
//   s_Wa rows: 256 shorts (512B, pow2) -> 3-bit key (e&7)<<3 on short index
//   s_tB rows: 160 shorts (320B, 10 o-chunks) -> 2-bit key (e&3)<<3
#define ESA  256           // Wa e-stride (shorts)
#define PBSA (16*ESA)      // Wa K-half stride
#define ESB  160           // tB e-stride (shorts)
#define PBSB (16*ESB)      // tB K-half stride
#define CGS  392           // s_cgy16 e-stride (shorts); 784B rows, 16B-aligned.
// LDS: Wa 16384 ; tB 10752 ; cgy16 12544 -> 39680 B -> 4 blocks/CU.
// Ledger of structural lessons:
//  R1: __launch_bounds__ min=5 crushes VGPRs -> 540MB scratch spill. Keep 4.
//  R6: fully-unrolled K-loop, runtime->compile-time path metadata: 357us.
//  R7: per-element device atomicAdd resolves at the cross-XCD coherent point:
//      36M atomics = +406MB RMW traffic, +257us. Never per-element atomics.
//  R8-R10: fused scatter exactly re-spends what it saves. Reverted.
//  R9: LDS 26.6KB did NOT raise residency past 4 blocks/CU.
//  R11: bf16 msg halves the round-trip: total 485->469. BEST.
//  R12-R14: permutation cost (~25us) is conserved wherever placed (input
//      gather / msg write / msg read). Gather-side eidx (R11) kept.
//  R15: cgY register double-buffer -- path p+1's cgY values prefetched into
//      statically-indexed registers during phase p (same pattern as rf),
//      removing the last in-phase LDS-read latency chain from the K-loop.
#define MINBPC 4

typedef __attribute__((ext_vector_type(8))) short bf16x8;
typedef __attribute__((ext_vector_type(4))) float f32x4;

// ---- per-path metadata (compile-time after full unroll) ----
__device__ const int   d_io[NP]  = {0,0,0, 1,1,1,1,1,1,1, 2,2,2,2, 2,2,2,2,2};
__device__ const int   d_ii[NP]  = {0,1,2, 0,1,1,1,2,2,2, 0,1,1,1, 2,2,2,2,2};
__device__ const int   d_lf[NP]  = {0,1,2, 1,0,1,2,1,2,3, 2,1,2,3, 0,1,2,3,4};
__device__ const int   d_cgb[NP] = {0,1,10, 35,44,53,80,125,170,245, 350,375,420,495, 600,625,700,825,1000};
// s_cgy16 per-path base (shorts). Non-overlapping packing, total 389 <= CGS=392:
//   dI=5: p2@0(8) p7@8(24) p8@32(24) p9@56(24) p14@80(40) p15@120(40)
//         p16@160(40) p17@200(40) p18@240(40)
//   dI=3: p1@280(4) p4@284(12) p5@296(12) p6@308(12) p11@320(20) p12@340(20) p13@360(20)
//   dI=1: p0@380(1) p3@381(3) p10@384(5)
__device__ const int   d_cgyb[NP] = {380,280,0, 381,284,296,308, 8,32,56, 384,320,340,360, 80,120,160,200,240};
__device__ const float d_nrm5[5] = {1.0f, 0.57735026918962576f, 0.44721359549995794f,
                                    0.37796447300922722f, 0.33333333333333333f};

__device__ __forceinline__ unsigned short to_bf16(float v) {
    __hip_bfloat16 h = __float2bfloat16(v);
    return *reinterpret_cast<unsigned short*>(&h);
}
__device__ __forceinline__ float bf2f(unsigned short u) {
    unsigned int x = ((unsigned int)u) << 16;
    union { unsigned int i; float f; } c; c.i = x;
    return c.f;
}

// ---- fused setup: R swizzle (first RTB blocks) + CSR count (rest) ----
__global__ void k_rtcount(const float* __restrict__ R, unsigned short* __restrict__ Rt,
                          const int* __restrict__ Ma, int* __restrict__ cur, int E) {
    const int RTB = (NP * 16 * 64 * 8) / BLK;      // 608 (exact)
    if ((int)blockIdx.x < RTB) {
        const int i = blockIdx.x * BLK + threadIdx.x;  // over NP*16*64*8
        const int j    = i & 7;
        const int lane = (i >> 3) & 63;
        const int t    = (i >> 9) & 15;
        const int p    = i >> 13;
        const int r    = (lane >> 4) * 8 + j;
        const int col  = p * 256 + 16 * t + (lane & 15);
        float v = (r < 10) ? R[r * RSTRIDE + col] : 0.f;
        Rt[i] = to_bf16(v);
    } else {
        const int e = (blockIdx.x - RTB) * BLK + threadIdx.x;
        if (e < E) atomicAdd(&cur[Ma[e]], 1);
    }
}

// ---------------- Phase A: edge-major; W-GEMM and msg-GEMM both on MFMA ----------------
__global__ __launch_bounds__(BLK, MINBPC)
void se3_msg(const float* __restrict__ F,
             const float* __restrict__ Ys, const float* __restrict__ Rad,
             const float* __restrict__ cg, const unsigned short* __restrict__ Rt,
             const int* __restrict__ Mb,
             unsigned short* __restrict__ msg, const int nE)
{
    __shared__ __align__(16) unsigned short s_Wa[2 * PBSA];        // Wstack A-frag (two K-halves)
    __shared__ __align__(16) unsigned short s_tB[2 * PBSB + 256];  // tmpstack B-frag + overrun pad
    __shared__ __align__(16) unsigned short s_cgy16[EPB * CGS];    // precomputed cgY (bf16 compact)

    const int tid  = threadIdx.x;
    const int l    = tid & 15;
    const int eloc = tid >> 4;
    const int lane = tid & 63;
    const int wv   = tid >> 6;
    const int q    = lane >> 4;
    const int n16  = lane & 15;
    const int e    = blockIdx.x * EPB + eloc;
    const bool act = (e < nE);
    const int  es  = act ? e : 0;

    // F slice -> registers (compile-time indexed)
    float fv[9];
    {
        const int b = Mb[es];
        const float* Fb = F + (size_t)b * 144;
        fv[0] = Fb[l];
        #pragma unroll
        for (int i = 0; i < 3; ++i) fv[1 + i] = Fb[16 + l*3 + i];
        #pragma unroll
        for (int i = 0; i < 5; ++i) fv[4 + i] = Fb[64 + l*5 + i];
    }
    // Ys row -> registers (dead after cgY prologue)
    float y[25];
    {
        const float* yr = Ys + (size_t)es * 25;
        #pragma unroll
        for (int k = 0; k < 25; ++k) y[k] = yr[k];
    }
    // radii fragment (B operand of MFMA-1): B[k=r][n=e], K zero-padded 10->32
    bf16x8 radfrag;
    {
        const int k0 = q * 8;
        const int ge = blockIdx.x * EPB + n16;
        const bool a = (ge < nE);
        const float* rp = Rad + (size_t)(a ? ge : 0) * 10;
        #pragma unroll
        for (int j = 0; j < 8; ++j) {
            const int k = k0 + j;
            radfrag[j] = (short)((a && k < 10) ? to_bf16(rp[k]) : (unsigned short)0);
        }
    }

    const int keyB = (eloc & 3) << 3;      // tB swizzle key for our row
    const int rowB = eloc * ESB;

    // tb one-time zero (maintained incrementally afterwards); 10 used chunks
    {
        #pragma unroll
        for (int n = 0; n < 10; ++n) {
            const int off = (rowB + (n << 4) + l) ^ keyB;
            s_tB[off] = 0; s_tB[PBSB + off] = 0;
        }
    }

    // ---- PROLOGUE: precompute ALL cgY (19 paths) into s_cgy16, bf16 compact ----
    {
        #pragma unroll
        for (int p = 0; p < NP; ++p) {
            const int io = d_io[p], ii = d_ii[p], lf = d_lf[p];
            const int cgb = d_cgb[p], cb = d_cgyb[p];
            const int dO = 2*io + 1, dI = 2*ii + 1, dF = 2*lf + 1;
            const int nOI = dO * dI;
            const float nrm = d_nrm5[lf];
            #pragma unroll
            for (int jj = 0; jj < 2; ++jj) {
                const int j = l + 16*jj;
                if (j < nOI) {            // pruned at compile time when nOI <= 16*jj
                    const int o = j / dI, i = j - o*dI;
                    const float* cgp = cg + cgb + j*dF;
                    float s = 0.f;
                    #pragma unroll
                    for (int f = 0; f < dF; ++f) s += cgp[f] * y[lf*lf + f];
                    const int off = (dI == 1) ? o : (dI == 3) ? (o*4 + i) : (o*8 + i);
                    s_cgy16[eloc*CGS + cb + off] = to_bf16(s * nrm);
                }
            }
        }
    }
    __asm__ volatile("" ::: "memory");   // cgY visible (intra-wave, DS in-order)

    // Rt prefetch double-buffer: rf[pb] holds path p's 4 fragments
    bf16x8 rf[2][4];
    {
        const unsigned short* r0 = Rt + (size_t)(4*wv)*512 + lane*8;
        #pragma unroll
        for (int tt = 0; tt < 4; ++tt) rf[0][tt] = *reinterpret_cast<const bf16x8*>(r0 + tt*512);
    }

    // cgY register double-buffer (R15): buffer [p&1] holds path p's values.
    // Statically indexed everywhere (full unroll) -> stays in registers.
    unsigned short cg1[2][5];      // dI==1 paths (scalar per o)
    short4         cg3[2][5];      // dI==3 paths (4-short rows)
    bf16x8         cgf[2][5];      // dI==5 paths (8-short rows)
    {
        // p0: ii=0, dO=1, cb=380
        cg1[0][0] = s_cgy16[eloc*CGS + 380];
    }

    f32x4 D[4];
    #pragma unroll
    for (int ee = 0; ee < 4; ++ee) D[ee] = (f32x4){0.f,0.f,0.f,0.f};

    // ---- K-block loop: FULLY UNROLLED. 10 x (2 paths staged -> 1 MFMA-2 K-step).
    #pragma unroll
    for (int kb = 0; kb < 10; ++kb) {
        #pragma unroll
        for (int pb = 0; pb < 2; ++pb) {
            const int p = 2*kb + pb;
            // prefetch next path's Rt fragments + cgY values into the other buffers
            if (p + 1 < NP) {
                const unsigned short* rn = Rt + (size_t)(p+1)*8192 + (size_t)(4*wv)*512 + lane*8;
                #pragma unroll
                for (int tt = 0; tt < 4; ++tt)
                    rf[pb ^ 1][tt] = *reinterpret_cast<const bf16x8*>(rn + tt*512);

                const int pn  = p + 1;
                const int iiN = d_ii[pn], ioN = d_io[pn], cbN = d_cgyb[pn];
                const int dON = 2*ioN + 1;
                const unsigned short* cgn = &s_cgy16[eloc*CGS + cbN];
                if (iiN == 0) {
                    #pragma unroll
                    for (int o = 0; o < dON; ++o) cg1[pb ^ 1][o] = cgn[o];
                } else if (iiN == 1) {
                    #pragma unroll
                    for (int o = 0; o < dON; ++o)
                        cg3[pb ^ 1][o] = *reinterpret_cast<const short4*>(&cgn[o*4]);
                } else {
                    #pragma unroll
                    for (int o = 0; o < dON; ++o)
                        cgf[pb ^ 1][o] = *reinterpret_cast<const bf16x8*>(&cgn[o*8]);
                }
            }
            if (p < NP) {
                // MFMA-1 (swapped): D = R_p^T(16c x 32k) @ rad^T(32k x 16e)
                #pragma unroll
                for (int tt = 0; tt < 4; ++tt) {
                    f32x4 d = __builtin_amdgcn_mfma_f32_16x16x32_bf16(
                                  rf[pb][tt], radfrag, (f32x4){0.f,0.f,0.f,0.f}, 0, 0, 0);
                    short4 pk;
                    pk.x = (short)to_bf16(d[0]); pk.y = (short)to_bf16(d[1]);
                    pk.z = (short)to_bf16(d[2]); pk.w = (short)to_bf16(d[3]);
                    const int w = 4*wv + tt;
                    *reinterpret_cast<short4*>(
                        &s_Wa[pb*PBSA + (((n16 << 8) + (w << 4) + (q << 2)) ^ ((n16 & 7) << 3))]) = pk;
                }

                // path metadata (compile-time constants after unroll)
                const int io = d_io[p], ii = d_ii[p];
                const int dO = 2*io + 1;
                const int ob  = (io == 0) ? 0 : (io == 1) ? 1 : 4;

                // tmp[v=l, o] -> B-frag bf16 [e][n=ob+o][v] from REGISTERS (R15);
                // zero only vacated slots.
                unsigned short* tbh = &s_tB[pb*PBSB];
                if (p == 3 || p == 4)        { tbh[(rowB + l) ^ keyB] = 0; }
                else if (p == 10 || p == 11) { tbh[(rowB + 16 + l) ^ keyB] = 0;
                                               tbh[(rowB + 32 + l) ^ keyB] = 0;
                                               tbh[(rowB + 48 + l) ^ keyB] = 0; }
                if (ii == 0) {
                    #pragma unroll
                    for (int o = 0; o < dO; ++o) {
                        const float c0 = bf2f(cg1[pb][o]);
                        tbh[(rowB + ((ob + o) << 4) + l) ^ keyB] = to_bf16(fv[0]*c0);
                    }
                } else if (ii == 1) {
                    #pragma unroll
                    for (int o = 0; o < dO; ++o) {
                        const short4 c = cg3[pb][o];
                        tbh[(rowB + ((ob + o) << 4) + l) ^ keyB] =
                            to_bf16(fv[1]*bf2f((unsigned short)c.x)
                                  + fv[2]*bf2f((unsigned short)c.y)
                                  + fv[3]*bf2f((unsigned short)c.z));
                    }
                } else {
                    #pragma unroll
                    for (int o = 0; o < dO; ++o) {
                        const bf16x8 c = cgf[pb][o];
                        tbh[(rowB + ((ob + o) << 4) + l) ^ keyB] =
                            to_bf16(fv[4]*bf2f((unsigned short)c[0])
                                  + fv[5]*bf2f((unsigned short)c[1])
                                  + fv[6]*bf2f((unsigned short)c[2])
                                  + fv[7]*bf2f((unsigned short)c[3])
                                  + fv[8]*bf2f((unsigned short)c[4]));
                    }
                }
            } else {
                // p == 19 pad: zero our W slots (A==0 kills stale tb of this K-half)
                const short4 z = {0, 0, 0, 0};
                #pragma unroll
                for (int tt = 0; tt < 4; ++tt) {
                    const int w = 4*wv + tt;
                    *reinterpret_cast<short4*>(
                        &s_Wa[pb*PBSA + (((n16 << 8) + (w << 4) + (q << 2)) ^ ((n16 & 7) << 3))]) = z;
                }
            }
        }
        __syncthreads();   // W (cross-wave w-tiles) staged for this K-block

        // MFMA-2 K-step: msg_e(16w x 16n) += Wstack_e(16x32) @ tmpstack_e(32x16)
        {
            const int kh = q >> 1;
            const int vh = (q & 1) << 3;
            #pragma unroll
            for (int ee = 0; ee < 4; ++ee) {
                const int eK   = 4*wv + ee;
                const bf16x8 Af = *reinterpret_cast<const bf16x8*>(
                    &s_Wa[kh*PBSA + (((eK << 8) + (n16 << 4) + vh) ^ ((eK & 7) << 3))]);
                const bf16x8 Bf = *reinterpret_cast<const bf16x8*>(
                    &s_tB[kh*PBSB + ((eK*ESB + (n16 << 4) + vh) ^ ((eK & 3) << 3))]);
                D[ee] = __builtin_amdgcn_mfma_f32_16x16x32_bf16(Af, Bf, D[ee], 0, 0, 0);
            }
        }
        __syncthreads();   // WAR: next K-block rewrites s_Wa / s_tB
    }

    // epilogue: D[row=w=q*4+r, col=oflat=n16] -> msg[e][oflat*16 + w] as bf16,
    // short4 (8B) stores; halves the msg round-trip vs fp32.
    if (n16 < 9) {
        #pragma unroll
        for (int ee = 0; ee < 4; ++ee) {
            const int eg = blockIdx.x * EPB + 4*wv + ee;
            if (eg < nE) {
                unsigned short* mp = msg + (size_t)eg * 144 + n16*16 + q*4;
                short4 pk;
                pk.x = (short)to_bf16(D[ee][0]); pk.y = (short)to_bf16(D[ee][1]);
                pk.z = (short)to_bf16(D[ee][2]); pk.w = (short)to_bf16(D[ee][3]);
                *reinterpret_cast<short4*>(mp) = pk;
            }
        }
    }
}

// ---------------- Phase B: node gather-reduce (no atomics, bf16 msg) ----------------
__global__ __launch_bounds__(BLK)
void se3_gather(const unsigned short* __restrict__ msg, const int* __restrict__ off,
                const int* __restrict__ eidx, const float* __restrict__ Nn,
                float* __restrict__ Out, const int nN)
{
    const int l = threadIdx.x & 15;
    const int g = threadIdx.x >> 4;
    const int n = blockIdx.x * 16 + g;
    if (n >= nN) return;

    const int i0 = off[n], i1 = off[n + 1];
    float s[9];
    #pragma unroll
    for (int j = 0; j < 9; ++j) s[j] = 0.f;

    for (int idx = i0; idx < i1; ++idx) {
        const int eid = eidx[idx];
        const unsigned short* m = msg + (size_t)eid * 144 + l;
        #pragma unroll
        for (int j = 0; j < 9; ++j) s[j] += bf2f(m[j * 16]);
    }

    const float nn = Nn[n];
    float* orow = Out + (size_t)n * 144;
    orow[l] = s[0] * nn;
    #pragma unroll
    for (int o = 0; o < 3; ++o) orow[16 + l*3 + o] = s[1+o] * nn;
    #pragma unroll
    for (int o = 0; o < 5; ++o) orow[64 + l*5 + o] = s[4+o] * nn;
}

// ---------------- CSR build (by destination) ----------------
__global__ void k_scan(int* __restrict__ cur, int* __restrict__ off, int N) {
    __shared__ int part[BLK];
    const int t = threadIdx.x;
    const int K = (N + BLK - 1) / BLK;
    const int i0 = t * K, i1 = min(i0 + K, N);
    int s = 0;
    for (int i = i0; i < i1; ++i) s += cur[i];
    part[t] = s;
    __syncthreads();
    if (t == 0) {
        int a = 0;
        for (int j = 0; j < BLK; ++j) { int v = part[j]; part[j] = a; a += v; }
        off[N] = a;
    }
    __syncthreads();
    int a = part[t];
    for (int i = i0; i < i1; ++i) {
        int v = cur[i];
        off[i] = a;
        cur[i] = a;       // reuse as scatter cursor
        a += v;
    }
}

__global__ void k_scatter(const int* __restrict__ Ma, int* __restrict__ cur,
                          int* __restrict__ eidx, int E) {
    int e = blockIdx.x * blockDim.x + threadIdx.x;
    if (e < E) {
        int pos = atomicAdd(&cur[Ma[e]], 1);
        eidx[pos] = e;
    }
}

extern "C" void kernel_launch(void* const* d_in, const int* in_sizes, int n_in,
                              void* d_out, int out_size, void* d_ws, size_t ws_size,
                              hipStream_t stream) {
    const float* F   = (const float*)d_in[0];
    const float* R   = (const float*)d_in[1];
    const float* Ys  = (const float*)d_in[2];
    const float* Rad = (const float*)d_in[3];
    const float* cg  = (const float*)d_in[4];
    const float* Nn  = (const float*)d_in[5];
    const int*   Ma  = (const int*)d_in[6];
    const int*   Mb  = (const int*)d_in[7];
    float* Out = (float*)d_out;

    const int nE = in_sizes[6];   // edges
    const int nN = in_sizes[5];   // nodes

    // ws layout (float units): [cur nN][off nN+1][eidx nE][pad]
    //   [msg nE*144 bf16 = nE*72 f32][pad][Rt NP*16*64*8 bf16]
    int* wsI  = (int*)d_ws;
    int* cur  = wsI;
    int* off  = wsI + nN;
    int* eidx = wsI + 2*nN + 1;
    size_t msgOff = ((size_t)(2*nN + 1 + nE) + 63) & ~(size_t)63;
    unsigned short* msg16 = (unsigned short*)((float*)d_ws + msgOff);
    size_t rtOff = ((msgOff + (size_t)nE * 72) + 63) & ~(size_t)63;
    unsigned short* Rt = (unsigned short*)((float*)d_ws + rtOff);

    const int RTB = (NP * 16 * 64 * 8) / BLK;          // 608
    const int CNT = (nE + BLK - 1) / BLK;

    hipMemsetAsync(cur, 0, (size_t)nN * sizeof(int), stream);
    k_rtcount<<<RTB + CNT, BLK, 0, stream>>>(R, Rt, Ma, cur, nE);
    k_scan   <<<1, BLK, 0, stream>>>(cur, off, nN);
    k_scatter<<<CNT, BLK, 0, stream>>>(Ma, cur, eidx, nE);

    se3_msg   <<<(nE + EPB - 1) / EPB, BLK, 0, stream>>>(F, Ys, Rad, cg, Rt, Mb, msg16, nE);
    se3_gather<<<(nN + 15) / 16, BLK, 0, stream>>>(msg16, off, eidx, Nn, Out, nN);
}